// Round 8
// baseline (303.019 us; speedup 1.0000x reference)
//
#include <hip/hip_runtime.h>
#include <stdint.h>

namespace {
constexpr int HW  = 1024;
constexpr int CH  = 3;
constexpr int IMG_N = 8 * CH * HW * HW;       // 25165824
constexpr int PLN   = 8 * HW * HW;            // 8388608
}

// global -> LDS direct DMA, 16B per lane. HW semantics (m104): writes
// lds_base_uniform + lane*16; global addr is per-lane.
__device__ __forceinline__ void gl_lds16(const void* g, void* l) {
    auto g1 = (const __attribute__((address_space(1))) uint32_t*)g;
    auto l3 = (__attribute__((address_space(3))) uint32_t*)l;
    __builtin_amdgcn_global_load_lds(g1, l3, 16, 0, 0);
}

__global__ __launch_bounds__(256)
void geo_perturb_kernel(const float* __restrict__ imgs,
                        const int*   __restrict__ lbls,
                        const float* __restrict__ pwin,
                        const float* __restrict__ theta,
                        float* __restrict__ out) {
    // Reference is unfused f32 numpy: round after EVERY op except the
    // deliberate FMAs in the inverse (OpenBLAS ger/trsm use FMA).
    #pragma clang fp contract(off)

    // Linear, UNPADDED layouts (required by global_load_lds). All reads are
    // row-parallel (bank = x mod 32, lane-monotonic) -> <=2-way, free.
    __shared__ __align__(16) float simg[CH * 32 * 32];   // [c][y][x]
    __shared__ __align__(16) int   slbl[32 * 32];
    __shared__ __align__(16) float spw [32 * 32];

    const int blk  = blockIdx.x;          // patch index n (B, gh, gw order)
    const int bi   = blk >> 10;
    const int gy   = (blk >> 5) & 31;
    const int gx   = blk & 31;
    const int t    = threadIdx.x;
    const int row0 = gy << 5;
    const int col0 = gx << 5;

    // ---- stage patch via global_load_lds (no transforms needed) ----
    {
        const int w  = t >> 6;            // wave 0..3 -> rows 8w..8w+7
        const int l  = t & 63;
        const int lr = l >> 3;            // row within wave chunk
        const int lc = (l & 7) << 2;      // float offset 0,4,...,28
        const int grow = row0 + (w << 3) + lr;
#pragma unroll
        for (int c = 0; c < CH; ++c) {
            gl_lds16(imgs + (((size_t)(bi * CH + c) * HW + grow) * HW + col0 + lc),
                     &simg[c * 1024 + (w << 8)]);
        }
        gl_lds16(lbls + (((size_t)bi * HW + grow) * HW + col0 + lc), &slbl[w << 8]);
        gl_lds16(pwin + (((size_t)bi * HW + grow) * HW + col0 + lc), &spw [w << 8]);
    }

    // ---- inverse affine mirroring numpy inv == LAPACK sgesv(A, I):
    //      sgetf2 (reciprocal-scale, FMA rank-1) + strsm (pre-inverted
    //      diagonals, FMA column updates). f32 throughout. (validated R5) ----
    const float* th = theta + blk * 6;
    const float a = th[0], b = th[1], c0 = th[2];
    const float d = th[3], e = th[4], f0 = th[5];

    const float ra  = 1.0f / a;
    const float l10 = d * ra;
    const float e2  = __builtin_fmaf(l10, -b,  e);
    const float f2  = __builtin_fmaf(l10, -c0, f0);
    const float r2  = 1.0f / e2;
    const float i11 = r2;
    const float i10 = -l10 * r2;
    const float i12 = -f2  * r2;
    const float i00 = __builtin_fmaf(-b, i10, 1.0f) * ra;
    const float i01 = (-b * i11) * ra;
    const float i02 = __builtin_fmaf(-b, i12, -c0) * ra;

    __syncthreads();   // compiler emits vmcnt(0) drain -> DMA complete

    float*       out_img = out;
    float*       out_lbl = out + IMG_N;
    float*       out_pw  = out + IMG_N + PLN;
    const int x = t & 31;                 // lane-consecutive x -> conflict-free LDS

#pragma unroll
    for (int it = 0; it < 4; ++it) {
        const int y = (t >> 5) + (it << 3);          // 0..31 across iterations
        const float xf = (float)x, yf = (float)y;
        // reference tree: (ti00*xs + ti01*ys) + ti02, unfused
        const float sx = (i00 * xf + i01 * yf) + i02;
        const float sy = (i10 * xf + i11 * yf) + i12;

        // ---- bilinear (image) — byte-identical arithmetic to R5 ----
        const float fx = floorf(sx), fy = floorf(sy);
        const float wx = sx - fx,    wy = sy - fy;
        const int x0 = (int)fx, y0 = (int)fy;
        const int x1 = x0 + 1,  y1 = y0 + 1;
        const bool bx0 = (x0 >= 0) && (x0 <= 31);
        const bool bx1 = (x1 >= 0) && (x1 <= 31);
        const bool by0 = (y0 >= 0) && (y0 <= 31);
        const bool by1 = (y1 >= 0) && (y1 <= 31);
        const float omwx = 1.0f - wx, omwy = 1.0f - wy;
        const float w00 = (bx0 && by0) ? (omwx * omwy) : 0.0f;
        const float w01 = (bx1 && by0) ? (wx   * omwy) : 0.0f;
        const float w10 = (bx0 && by1) ? (omwx * wy)   : 0.0f;
        const float w11 = (bx1 && by1) ? (wx   * wy)   : 0.0f;
        const int xc0 = min(max(x0, 0), 31), yc0 = min(max(y0, 0), 31);
        const int xc1 = min(max(x1, 0), 31), yc1 = min(max(y1, 0), 31);

#pragma unroll
        for (int c = 0; c < CH; ++c) {
            const float* sc = &simg[c * 1024];
            const float t00 = sc[yc0 * 32 + xc0] * w00;
            const float t01 = sc[yc0 * 32 + xc1] * w01;
            const float t10 = sc[yc1 * 32 + xc0] * w10;
            const float t11 = sc[yc1 * 32 + xc1] * w11;
            const float v = ((t00 + t01) + t10) + t11;
            const float o = (v == 0.0f) ? sc[y * 32 + x] : v;   // holes <- original
            out_img[((size_t)(bi * CH + c) * HW + row0 + y) * HW + col0 + x] = o;
        }

        // ---- nearest (labels + pweight): sentinel logic collapses exactly to
        //      final = inb ? raw[cell] : raw[self]  (proved case-wise) ----
        const int xi = (int)rintf(sx);
        const int yi = (int)rintf(sy);
        const bool nin = (xi >= 0) && (xi <= 31) && (yi >= 0) && (yi <= 31);
        const int xcn = min(max(xi, 0), 31), ycn = min(max(yi, 0), 31);

        const int   ol = nin ? slbl[ycn * 32 + xcn] : slbl[y * 32 + x];
        const float op = nin ? spw [ycn * 32 + xcn] : spw [y * 32 + x];
        out_lbl[((size_t)bi * HW + row0 + y) * HW + col0 + x] = (float)ol;
        out_pw [((size_t)bi * HW + row0 + y) * HW + col0 + x] = op;
    }
}

extern "C" void kernel_launch(void* const* d_in, const int* in_sizes, int n_in,
                              void* d_out, int out_size, void* d_ws, size_t ws_size,
                              hipStream_t stream) {
    const float* imgs  = (const float*)d_in[0];
    const int*   lbls  = (const int*)  d_in[1];
    const float* pwin  = (const float*)d_in[2];
    const float* theta = (const float*)d_in[3];
    float* out = (float*)d_out;
    (void)in_sizes; (void)n_in; (void)out_size; (void)d_ws; (void)ws_size;

    dim3 grid(8192), block(256);
    hipLaunchKernelGGL(geo_perturb_kernel, grid, block, 0, stream,
                       imgs, lbls, pwin, theta, out);
}